// Round 12
// baseline (261.601 us; speedup 1.0000x reference)
//
#include <hip/hip_runtime.h>
#include <math.h>

#define NN 10000
#define EE 160000
#define DIM 256
#define KK 512            // concatenated K = 2*DIM
#define CAP 128           // bucket capacity (max deg ~45 for mean-16 degrees)
#define EPS_BN 1e-5f
#define AST 516           // LDS A-tile row stride in shorts (1032 B = 8B-aligned, 2-way banks)

typedef __attribute__((ext_vector_type(8)))  short bf16x8;
typedef __attribute__((ext_vector_type(16))) float f32x16;

union U16 { uint2 u2[2]; bf16x8 v; };

static __device__ __forceinline__ unsigned short f2bf(float f) {
    unsigned u = __float_as_uint(f);
    unsigned r = (u + 0x7fffu + ((u >> 16) & 1u)) >> 16;   // RTNE
    return (unsigned short)r;
}
static __device__ __forceinline__ float bflo(unsigned v) { return __uint_as_float(v << 16); }
static __device__ __forceinline__ float bfhi(unsigned v) { return __uint_as_float(v & 0xffff0000u); }
static __device__ __forceinline__ unsigned packbf(float a, float b) {
    return (unsigned)f2bf(a) | ((unsigned)f2bf(b) << 16);
}

struct Params {
    const float* x; const int* src; const int* dst;
    const float *Ws0, *Wn0, *Ws1, *Wn1, *Ws2, *Wn2;
    const float *g0, *be0, *g1, *be1, *g2, *be2;
    float* out;
    unsigned short* hx;     // [NN][DIM] bf16 x   (row = 32 uint4)
    unsigned short* z0;     // [NN][DIM] bf16 z ping
    unsigned short* z1;     // [NN][DIM] bf16 z pong
    unsigned short* wcat;   // [3][DIM][KK] bf16, [n][k]
    float* stats;           // [3][2*DIM]
    int* cnt;               // [NN]
    int* slots;             // [NN][CAP]
};

static __device__ __forceinline__ void accum8(float* a, uint4 v) {
    a[0] += bflo(v.x); a[1] += bfhi(v.x);
    a[2] += bflo(v.y); a[3] += bfhi(v.y);
    a[4] += bflo(v.z); a[5] += bfhi(v.z);
    a[6] += bflo(v.w); a[7] += bfhi(v.w);
}
static __device__ __forceinline__ void accum8n(float* a, uint4 v,
                                               const float* sc, const float* sh) {
    a[0] += fmaxf(bflo(v.x) * sc[0] + sh[0], 0.f);
    a[1] += fmaxf(bfhi(v.x) * sc[1] + sh[1], 0.f);
    a[2] += fmaxf(bflo(v.y) * sc[2] + sh[2], 0.f);
    a[3] += fmaxf(bfhi(v.y) * sc[3] + sh[3], 0.f);
    a[4] += fmaxf(bflo(v.z) * sc[4] + sh[4], 0.f);
    a[5] += fmaxf(bfhi(v.z) * sc[5] + sh[5], 0.f);
    a[6] += fmaxf(bflo(v.w) * sc[6] + sh[6], 0.f);
    a[7] += fmaxf(bfhi(v.w) * sc[7] + sh[7], 0.f);
}

// ---------------- prep: converts + zeroing (R10 verbatim) ----------------
__global__ __launch_bounds__(256) void k_prep(Params P) {
    int g0 = blockIdx.x * 256 + threadIdx.x;
    int stride = gridDim.x * 256;
    for (int g = g0; g < NN * 64; g += stride) {            // x -> hx bf16 [NN][256]
        int r = g >> 6, c4 = (g & 63) * 4;
        float4 v = *(const float4*)(P.x + (size_t)r * DIM + c4);
        uint2 p; p.x = packbf(v.x, v.y); p.y = packbf(v.z, v.w);
        *(uint2*)(P.hx + (size_t)r * DIM + c4) = p;
    }
    for (int g = g0; g < 3 * DIM * KK; g += stride) {       // [Ws;Wn] -> wcat [n][k]
        int L = g >> 17; int i = g & 131071;
        int k = i >> 8, n = i & 255;
        const float* Ws = (L == 0) ? P.Ws0 : ((L == 1) ? P.Ws1 : P.Ws2);
        const float* Wn = (L == 0) ? P.Wn0 : ((L == 1) ? P.Wn1 : P.Wn2);
        float v = (k < DIM) ? Ws[(size_t)k * DIM + n] : Wn[(size_t)(k - DIM) * DIM + n];
        P.wcat[(size_t)L * DIM * KK + (size_t)n * KK + k] = f2bf(v);
    }
    for (int g = g0; g < NN + 6 * DIM; g += stride) {
        if (g < NN) P.cnt[g] = 0;
        else P.stats[g - NN] = 0.f;
    }
}

// ---------------- bucket build (R9-proven) ----------------
__global__ __launch_bounds__(256) void k_bucket(Params P) {
    int e = blockIdx.x * 256 + threadIdx.x;
    if (e < EE) {
        int d = P.dst[e];
        int p = atomicAdd(&P.cnt[d], 1);
        if (p < CAP) P.slots[(size_t)d * CAP + p] = P.src[e];
    }
}

// ---------------- fused agg + GEMM + stats, one layer ----------------
// grid = 313 x 512 threads (8 waves). Phase A: wave gathers 4 nodes (wave-per-
// node mapping, half-waves interleave edges, 8-deep unroll = 16 uint4 loads in
// flight per wave) into LDS A-tile [32][512] (+ own rows, BN+relu for L>0).
// Phase B: R10-verbatim; wave w = cols w*32..w*32+31, A from LDS.
// Ping-pong: gsrc != gdst always.
__global__ __launch_bounds__(512) void k_ag(Params P, int L,
                                            const unsigned short* __restrict__ gsrc,
                                            unsigned short* __restrict__ gdst) {
    __shared__ unsigned short At[32][AST];                  // 33 KB
    int t = threadIdx.x;
    int wave = t >> 6, lane = t & 63;
    int h = lane >> 5, l = lane & 31;

    float sc[8], sh[8];
    if (L > 0) {                                            // BN affine of prev layer
        const float* st = P.stats + (L - 1) * 2 * DIM;
        const float* gam = (L == 1) ? P.g0 : P.g1;
        const float* bet = (L == 1) ? P.be0 : P.be1;
#pragma unroll
        for (int i = 0; i < 8; ++i) {
            int c = l * 8 + i;
            float mu  = st[c] * (1.0f / NN);
            float var = st[DIM + c] * (1.0f / NN) - mu * mu;
            float k = rsqrtf(var + EPS_BN) * gam[c];
            sc[i] = k;
            sh[i] = bet[c] - mu * k;
        }
    }
    const uint4* srcm = (const uint4*)gsrc;                 // rows = 32 uint4

    // ================= phase A: wave per node, 4 nodes =================
    for (int i = 0; i < 4; ++i) {
        int m = wave * 4 + i;                               // 8 waves x 4 = 32 rows
        int node = blockIdx.x * 32 + m;
        unsigned short* arow = &At[m][0];
        if (node >= NN) {
            if (h == 0) {
                uint2 z2 = make_uint2(0u, 0u);
                *(uint2*)(arow + l * 8)           = z2;
                *(uint2*)(arow + l * 8 + 4)       = z2;
                *(uint2*)(arow + 256 + l * 8)     = z2;
                *(uint2*)(arow + 256 + l * 8 + 4) = z2;
            }
            continue;
        }
        int cnt = P.cnt[node]; if (cnt > CAP) cnt = CAP;
        const int* sl = P.slots + (size_t)node * CAP;
        if (h == 0) {                                       // own row -> A left half
            uint4 z = srcm[(size_t)node * 32 + l];
            uint4 o;
            if (L > 0) {
                o.x = packbf(fmaxf(bflo(z.x) * sc[0] + sh[0], 0.f),
                             fmaxf(bfhi(z.x) * sc[1] + sh[1], 0.f));
                o.y = packbf(fmaxf(bflo(z.y) * sc[2] + sh[2], 0.f),
                             fmaxf(bfhi(z.y) * sc[3] + sh[3], 0.f));
                o.z = packbf(fmaxf(bflo(z.z) * sc[4] + sh[4], 0.f),
                             fmaxf(bfhi(z.z) * sc[5] + sh[5], 0.f));
                o.w = packbf(fmaxf(bflo(z.w) * sc[6] + sh[6], 0.f),
                             fmaxf(bfhi(z.w) * sc[7] + sh[7], 0.f));
            } else o = z;
            *(uint2*)(arow + l * 8)     = make_uint2(o.x, o.y);
            *(uint2*)(arow + l * 8 + 4) = make_uint2(o.z, o.w);
        }
        float a[8] = {0, 0, 0, 0, 0, 0, 0, 0};
        int j = h;                                          // half-waves interleave edges
        if (L == 0) {
            for (; j + 14 < cnt; j += 16) {                 // 8 loads in flight/half
                uint4 v0 = srcm[(size_t)sl[j +  0] * 32 + l];
                uint4 v1 = srcm[(size_t)sl[j +  2] * 32 + l];
                uint4 v2 = srcm[(size_t)sl[j +  4] * 32 + l];
                uint4 v3 = srcm[(size_t)sl[j +  6] * 32 + l];
                uint4 v4 = srcm[(size_t)sl[j +  8] * 32 + l];
                uint4 v5 = srcm[(size_t)sl[j + 10] * 32 + l];
                uint4 v6 = srcm[(size_t)sl[j + 12] * 32 + l];
                uint4 v7 = srcm[(size_t)sl[j + 14] * 32 + l];
                accum8(a, v0); accum8(a, v1); accum8(a, v2); accum8(a, v3);
                accum8(a, v4); accum8(a, v5); accum8(a, v6); accum8(a, v7);
            }
            for (; j + 6 < cnt; j += 8) {
                uint4 v0 = srcm[(size_t)sl[j + 0] * 32 + l];
                uint4 v1 = srcm[(size_t)sl[j + 2] * 32 + l];
                uint4 v2 = srcm[(size_t)sl[j + 4] * 32 + l];
                uint4 v3 = srcm[(size_t)sl[j + 6] * 32 + l];
                accum8(a, v0); accum8(a, v1); accum8(a, v2); accum8(a, v3);
            }
            for (; j < cnt; j += 2) accum8(a, srcm[(size_t)sl[j] * 32 + l]);
        } else {
            for (; j + 14 < cnt; j += 16) {
                uint4 v0 = srcm[(size_t)sl[j +  0] * 32 + l];
                uint4 v1 = srcm[(size_t)sl[j +  2] * 32 + l];
                uint4 v2 = srcm[(size_t)sl[j +  4] * 32 + l];
                uint4 v3 = srcm[(size_t)sl[j +  6] * 32 + l];
                uint4 v4 = srcm[(size_t)sl[j +  8] * 32 + l];
                uint4 v5 = srcm[(size_t)sl[j + 10] * 32 + l];
                uint4 v6 = srcm[(size_t)sl[j + 12] * 32 + l];
                uint4 v7 = srcm[(size_t)sl[j + 14] * 32 + l];
                accum8n(a, v0, sc, sh); accum8n(a, v1, sc, sh);
                accum8n(a, v2, sc, sh); accum8n(a, v3, sc, sh);
                accum8n(a, v4, sc, sh); accum8n(a, v5, sc, sh);
                accum8n(a, v6, sc, sh); accum8n(a, v7, sc, sh);
            }
            for (; j + 6 < cnt; j += 8) {
                uint4 v0 = srcm[(size_t)sl[j + 0] * 32 + l];
                uint4 v1 = srcm[(size_t)sl[j + 2] * 32 + l];
                uint4 v2 = srcm[(size_t)sl[j + 4] * 32 + l];
                uint4 v3 = srcm[(size_t)sl[j + 6] * 32 + l];
                accum8n(a, v0, sc, sh); accum8n(a, v1, sc, sh);
                accum8n(a, v2, sc, sh); accum8n(a, v3, sc, sh);
            }
            for (; j < cnt; j += 2) accum8n(a, srcm[(size_t)sl[j] * 32 + l], sc, sh);
        }
#pragma unroll
        for (int q = 0; q < 8; ++q) a[q] += __shfl_xor(a[q], 32);
        if (h == 0) {                                       // mean -> A right half
            float inv = 1.0f / (float)(cnt > 1 ? cnt : 1);
            *(uint2*)(arow + 256 + l * 8)     = make_uint2(packbf(a[0] * inv, a[1] * inv),
                                                           packbf(a[2] * inv, a[3] * inv));
            *(uint2*)(arow + 256 + l * 8 + 4) = make_uint2(packbf(a[4] * inv, a[5] * inv),
                                                           packbf(a[6] * inv, a[7] * inv));
        }
    }
    __syncthreads();

    // ================= phase B (R10 verbatim; A from LDS) =================
    const unsigned short* wcatL = P.wcat + (size_t)L * DIM * KK;
    float* statsL = P.stats + L * 2 * DIM;
    int m = l;
    int row0 = blockIdx.x * 32;
    int colw0 = wave * 32;                                  // 8 waves x 32 = 256 cols
    const unsigned short* Bp = wcatL + (size_t)(colw0 + m) * KK + h * 8;
    const unsigned short* Arow = &At[m][0];
    f32x16 acc;
#pragma unroll
    for (int i = 0; i < 16; ++i) acc[i] = 0.f;
#pragma unroll 8
    for (int k0 = 0; k0 < KK; k0 += 16) {
        U16 ua;
        ua.u2[0] = *(const uint2*)(Arow + k0 + h * 8);
        ua.u2[1] = *(const uint2*)(Arow + k0 + h * 8 + 4);
        bf16x8 av = ua.v;
        bf16x8 bv = *(const bf16x8*)(Bp + k0);
        acc = __builtin_amdgcn_mfma_f32_32x32x16_bf16(av, bv, acc, 0, 0, 0);
    }
    int cc = colw0 + m;
    float s = 0.f, s2 = 0.f;
#pragma unroll
    for (int reg = 0; reg < 16; ++reg) {
        int r = row0 + (reg & 3) + 8 * (reg >> 2) + 4 * h;
        if (r < NN) {
            float v = acc[reg];
            gdst[(size_t)r * DIM + cc] = f2bf(v);
            s += v; s2 += v * v;
        }
    }
    s  += __shfl_down(s, 32);
    s2 += __shfl_down(s2, 32);
    if (h == 0) {
        atomicAdd(&statsL[cc], s);
        atomicAdd(&statsL[DIM + cc], s2);
    }
}

// ---------------- final BN + sigmoid -> out (R10 verbatim) ----------------
__global__ __launch_bounds__(256) void k_norm(Params P) {
    const float* statsL = P.stats + 2 * 2 * DIM;
    int t = threadIdx.x;
    int c8 = (t & 31) * 8;
    int r = blockIdx.x * 8 + (t >> 5);                      // grid 1250
    float sc[8], sh[8];
#pragma unroll
    for (int i = 0; i < 8; ++i) {
        int c = c8 + i;
        float mu  = statsL[c] * (1.0f / NN);
        float var = statsL[DIM + c] * (1.0f / NN) - mu * mu;
        float k = rsqrtf(var + EPS_BN) * P.g2[c];
        sc[i] = k;
        sh[i] = P.be2[c] - mu * k;
    }
    uint4 v = *(const uint4*)(P.z0 + (size_t)r * DIM + c8);
    float f[8] = {bflo(v.x), bfhi(v.x), bflo(v.y), bfhi(v.y),
                  bflo(v.z), bfhi(v.z), bflo(v.w), bfhi(v.w)};
#pragma unroll
    for (int i = 0; i < 8; ++i) f[i] = f[i] * sc[i] + sh[i];
    float4 o0, o1;
    o0.x = 1.0f / (1.0f + __expf(-f[0]));
    o0.y = 1.0f / (1.0f + __expf(-f[1]));
    o0.z = 1.0f / (1.0f + __expf(-f[2]));
    o0.w = 1.0f / (1.0f + __expf(-f[3]));
    o1.x = 1.0f / (1.0f + __expf(-f[4]));
    o1.y = 1.0f / (1.0f + __expf(-f[5]));
    o1.z = 1.0f / (1.0f + __expf(-f[6]));
    o1.w = 1.0f / (1.0f + __expf(-f[7]));
    *(float4*)(P.out + (size_t)r * DIM + c8)     = o0;
    *(float4*)(P.out + (size_t)r * DIM + c8 + 4) = o1;
}

extern "C" void kernel_launch(void* const* d_in, const int* in_sizes, int n_in,
                              void* d_out, int out_size, void* d_ws, size_t ws_size,
                              hipStream_t stream) {
    Params P;
    P.x   = (const float*)d_in[0];
    P.src = (const int*)d_in[1];
    P.dst = (const int*)d_in[2];
    P.Ws0 = (const float*)d_in[3];  P.Wn0 = (const float*)d_in[4];
    P.g0  = (const float*)d_in[6];  P.be0 = (const float*)d_in[7];
    P.Ws1 = (const float*)d_in[8];  P.Wn1 = (const float*)d_in[9];
    P.g1  = (const float*)d_in[11]; P.be1 = (const float*)d_in[12];
    P.Ws2 = (const float*)d_in[13]; P.Wn2 = (const float*)d_in[14];
    P.g2  = (const float*)d_in[16]; P.be2 = (const float*)d_in[17];
    P.out = (float*)d_out;

    char* ws = (char*)d_ws;
    size_t off = 0;
    P.hx   = (unsigned short*)(ws + off); off += (size_t)NN * DIM * 2;       // 5.12 MB
    P.z0   = (unsigned short*)(ws + off); off += (size_t)NN * DIM * 2;       // 5.12 MB
    P.z1   = (unsigned short*)(ws + off); off += (size_t)NN * DIM * 2;       // 5.12 MB
    P.wcat = (unsigned short*)(ws + off); off += (size_t)3 * DIM * KK * 2;   // 0.79 MB
    P.stats = (float*)(ws + off); off += 3 * 2 * DIM * sizeof(float);
    P.cnt   = (int*)(ws + off); off += (size_t)NN * 4; off = (off + 255) & ~(size_t)255;
    P.slots = (int*)(ws + off); off += (size_t)NN * CAP * 4;                 // 5.12 MB
    (void)ws_size;

    k_prep<<<512, 256, 0, stream>>>(P);
    k_bucket<<<(EE + 255) / 256, 256, 0, stream>>>(P);
    // ping-pong: L0 hx->z0, L1 z0->z1, L2 z1->z0 (gather src != gemm dst)
    k_ag<<<313, 512, 0, stream>>>(P, 0, P.hx, P.z0);
    k_ag<<<313, 512, 0, stream>>>(P, 1, P.z0, P.z1);
    k_ag<<<313, 512, 0, stream>>>(P, 2, P.z1, P.z0);
    k_norm<<<NN / 8, 256, 0, stream>>>(P);
}

// Round 13
// 255.908 us; speedup vs baseline: 1.0222x; 1.0222x over previous
//
#include <hip/hip_runtime.h>
#include <math.h>

#define NN 10000
#define EE 160000
#define DIM 256
#define KK 512            // concatenated K = 2*DIM
#define CAP 128           // bucket capacity (max deg ~45 for mean-16 degrees)
#define EPS_BN 1e-5f
#define AST 516           // LDS A-tile row stride in shorts (1032 B = 8B-aligned, 2-way banks)

typedef __attribute__((ext_vector_type(8))) short bf16x8;
typedef __attribute__((ext_vector_type(4))) float f32x4;

union U16 { uint2 u2[2]; bf16x8 v; };

static __device__ __forceinline__ unsigned short f2bf(float f) {
    unsigned u = __float_as_uint(f);
    unsigned r = (u + 0x7fffu + ((u >> 16) & 1u)) >> 16;   // RTNE
    return (unsigned short)r;
}
static __device__ __forceinline__ float bflo(unsigned v) { return __uint_as_float(v << 16); }
static __device__ __forceinline__ float bfhi(unsigned v) { return __uint_as_float(v & 0xffff0000u); }
static __device__ __forceinline__ unsigned packbf(float a, float b) {
    return (unsigned)f2bf(a) | ((unsigned)f2bf(b) << 16);
}

struct Params {
    const float* x; const int* src; const int* dst;
    const float *Ws0, *Wn0, *Ws1, *Wn1, *Ws2, *Wn2;
    const float *g0, *be0, *g1, *be1, *g2, *be2;
    float* out;
    unsigned short* hx;     // [NN][DIM] bf16 x   (row = 32 uint4)
    unsigned short* z0;     // [NN][DIM] bf16 z ping
    unsigned short* z1;     // [NN][DIM] bf16 z pong
    unsigned short* wcat;   // [3][DIM][KK] bf16, [n][k]
    float* stats;           // [3][2*DIM]
    int* cnt;               // [NN]
    int* slots;             // [NN][CAP]
};

static __device__ __forceinline__ void accum8(float* a, uint4 v) {
    a[0] += bflo(v.x); a[1] += bfhi(v.x);
    a[2] += bflo(v.y); a[3] += bfhi(v.y);
    a[4] += bflo(v.z); a[5] += bfhi(v.z);
    a[6] += bflo(v.w); a[7] += bfhi(v.w);
}
static __device__ __forceinline__ void accum8n(float* a, uint4 v,
                                               const float* sc, const float* sh) {
    a[0] += fmaxf(bflo(v.x) * sc[0] + sh[0], 0.f);
    a[1] += fmaxf(bfhi(v.x) * sc[1] + sh[1], 0.f);
    a[2] += fmaxf(bflo(v.y) * sc[2] + sh[2], 0.f);
    a[3] += fmaxf(bfhi(v.y) * sc[3] + sh[3], 0.f);
    a[4] += fmaxf(bflo(v.z) * sc[4] + sh[4], 0.f);
    a[5] += fmaxf(bfhi(v.z) * sc[5] + sh[5], 0.f);
    a[6] += fmaxf(bflo(v.w) * sc[6] + sh[6], 0.f);
    a[7] += fmaxf(bfhi(v.w) * sc[7] + sh[7], 0.f);
}

// ---------------- prep: converts + zeroing (R10 verbatim) ----------------
__global__ __launch_bounds__(256) void k_prep(Params P) {
    int g0 = blockIdx.x * 256 + threadIdx.x;
    int stride = gridDim.x * 256;
    for (int g = g0; g < NN * 64; g += stride) {            // x -> hx bf16 [NN][256]
        int r = g >> 6, c4 = (g & 63) * 4;
        float4 v = *(const float4*)(P.x + (size_t)r * DIM + c4);
        uint2 p; p.x = packbf(v.x, v.y); p.y = packbf(v.z, v.w);
        *(uint2*)(P.hx + (size_t)r * DIM + c4) = p;
    }
    for (int g = g0; g < 3 * DIM * KK; g += stride) {       // [Ws;Wn] -> wcat [n][k]
        int L = g >> 17; int i = g & 131071;
        int k = i >> 8, n = i & 255;
        const float* Ws = (L == 0) ? P.Ws0 : ((L == 1) ? P.Ws1 : P.Ws2);
        const float* Wn = (L == 0) ? P.Wn0 : ((L == 1) ? P.Wn1 : P.Wn2);
        float v = (k < DIM) ? Ws[(size_t)k * DIM + n] : Wn[(size_t)(k - DIM) * DIM + n];
        P.wcat[(size_t)L * DIM * KK + (size_t)n * KK + k] = f2bf(v);
    }
    for (int g = g0; g < NN + 6 * DIM; g += stride) {
        if (g < NN) P.cnt[g] = 0;
        else P.stats[g - NN] = 0.f;
    }
}

// ---------------- bucket build (R9-proven) ----------------
__global__ __launch_bounds__(256) void k_bucket(Params P) {
    int e = blockIdx.x * 256 + threadIdx.x;
    if (e < EE) {
        int d = P.dst[e];
        int p = atomicAdd(&P.cnt[d], 1);
        if (p < CAP) P.slots[(size_t)d * CAP + p] = P.src[e];
    }
}

// ---------------- fused agg + GEMM + stats, one layer ----------------
// grid = 626 x 512 threads (8 waves); block = 16 rows x 256 cols.
// Phase A: wave gathers 2 nodes (R10-proven loop: wave-per-node, half-waves
//          interleave edges, 4-deep unroll) into LDS A-tile [16][512]
//          (+ own rows, BN+relu-normalized for L>0).
// Phase B: wave w = cols w*32..w*32+31 via two 16x16x32 MFMA chains; A from
//          LDS (m=lane&15, k=(lane>>4)*8), B from wcat [n][k].
// Ping-pong: gsrc != gdst always.
__global__ __launch_bounds__(512) void k_ag(Params P, int L,
                                            const unsigned short* __restrict__ gsrc,
                                            unsigned short* __restrict__ gdst) {
    __shared__ unsigned short At[16][AST];                  // 16.5 KB
    int t = threadIdx.x;
    int wave = t >> 6, lane = t & 63;
    int h = lane >> 5, l = lane & 31;

    float sc[8], sh[8];
    if (L > 0) {                                            // BN affine of prev layer
        const float* st = P.stats + (L - 1) * 2 * DIM;
        const float* gam = (L == 1) ? P.g0 : P.g1;
        const float* bet = (L == 1) ? P.be0 : P.be1;
#pragma unroll
        for (int i = 0; i < 8; ++i) {
            int c = l * 8 + i;
            float mu  = st[c] * (1.0f / NN);
            float var = st[DIM + c] * (1.0f / NN) - mu * mu;
            float k = rsqrtf(var + EPS_BN) * gam[c];
            sc[i] = k;
            sh[i] = bet[c] - mu * k;
        }
    }
    const uint4* srcm = (const uint4*)gsrc;                 // rows = 32 uint4

    // ================= phase A: wave per node, 2 nodes =================
    for (int i = 0; i < 2; ++i) {
        int m = wave * 2 + i;                               // 8 waves x 2 = 16 rows
        int node = blockIdx.x * 16 + m;
        unsigned short* arow = &At[m][0];
        if (node >= NN) {
            if (h == 0) {
                uint2 z2 = make_uint2(0u, 0u);
                *(uint2*)(arow + l * 8)           = z2;
                *(uint2*)(arow + l * 8 + 4)       = z2;
                *(uint2*)(arow + 256 + l * 8)     = z2;
                *(uint2*)(arow + 256 + l * 8 + 4) = z2;
            }
            continue;
        }
        int cnt = P.cnt[node]; if (cnt > CAP) cnt = CAP;
        const int* sl = P.slots + (size_t)node * CAP;
        if (h == 0) {                                       // own row -> A left half
            uint4 z = srcm[(size_t)node * 32 + l];
            uint4 o;
            if (L > 0) {
                o.x = packbf(fmaxf(bflo(z.x) * sc[0] + sh[0], 0.f),
                             fmaxf(bfhi(z.x) * sc[1] + sh[1], 0.f));
                o.y = packbf(fmaxf(bflo(z.y) * sc[2] + sh[2], 0.f),
                             fmaxf(bfhi(z.y) * sc[3] + sh[3], 0.f));
                o.z = packbf(fmaxf(bflo(z.z) * sc[4] + sh[4], 0.f),
                             fmaxf(bfhi(z.z) * sc[5] + sh[5], 0.f));
                o.w = packbf(fmaxf(bflo(z.w) * sc[6] + sh[6], 0.f),
                             fmaxf(bfhi(z.w) * sc[7] + sh[7], 0.f));
            } else o = z;
            *(uint2*)(arow + l * 8)     = make_uint2(o.x, o.y);
            *(uint2*)(arow + l * 8 + 4) = make_uint2(o.z, o.w);
        }
        float a[8] = {0, 0, 0, 0, 0, 0, 0, 0};
        int j = h;                                          // half-waves interleave edges
        if (L == 0) {
            for (; j + 6 < cnt; j += 8) {
                uint4 v0 = srcm[(size_t)sl[j + 0] * 32 + l];
                uint4 v1 = srcm[(size_t)sl[j + 2] * 32 + l];
                uint4 v2 = srcm[(size_t)sl[j + 4] * 32 + l];
                uint4 v3 = srcm[(size_t)sl[j + 6] * 32 + l];
                accum8(a, v0); accum8(a, v1); accum8(a, v2); accum8(a, v3);
            }
            for (; j < cnt; j += 2) accum8(a, srcm[(size_t)sl[j] * 32 + l]);
        } else {
            for (; j + 6 < cnt; j += 8) {
                uint4 v0 = srcm[(size_t)sl[j + 0] * 32 + l];
                uint4 v1 = srcm[(size_t)sl[j + 2] * 32 + l];
                uint4 v2 = srcm[(size_t)sl[j + 4] * 32 + l];
                uint4 v3 = srcm[(size_t)sl[j + 6] * 32 + l];
                accum8n(a, v0, sc, sh); accum8n(a, v1, sc, sh);
                accum8n(a, v2, sc, sh); accum8n(a, v3, sc, sh);
            }
            for (; j < cnt; j += 2) accum8n(a, srcm[(size_t)sl[j] * 32 + l], sc, sh);
        }
#pragma unroll
        for (int q = 0; q < 8; ++q) a[q] += __shfl_xor(a[q], 32);
        if (h == 0) {                                       // mean -> A right half
            float inv = 1.0f / (float)(cnt > 1 ? cnt : 1);
            *(uint2*)(arow + 256 + l * 8)     = make_uint2(packbf(a[0] * inv, a[1] * inv),
                                                           packbf(a[2] * inv, a[3] * inv));
            *(uint2*)(arow + 256 + l * 8 + 4) = make_uint2(packbf(a[4] * inv, a[5] * inv),
                                                           packbf(a[6] * inv, a[7] * inv));
        }
    }
    __syncthreads();

    // ================= phase B: two 16x16x32 MFMA chains per wave =================
    const unsigned short* wcatL = P.wcat + (size_t)L * DIM * KK;
    float* statsL = P.stats + L * 2 * DIM;
    int n16 = lane & 15;                                    // A row / B col / C col
    int q   = lane >> 4;                                    // 0..3: k-quad / C row group
    int row0 = blockIdx.x * 16;
    int colw0 = wave * 32;                                  // 8 waves x 32 = 256 cols
    const unsigned short* Arow = &At[n16][0];
    const unsigned short* Bp0 = wcatL + (size_t)(colw0 + n16) * KK + q * 8;
    const unsigned short* Bp1 = Bp0 + (size_t)16 * KK;
    f32x4 acc0, acc1;
#pragma unroll
    for (int i = 0; i < 4; ++i) { acc0[i] = 0.f; acc1[i] = 0.f; }
#pragma unroll 8
    for (int k0 = 0; k0 < KK; k0 += 32) {
        U16 ua;
        ua.u2[0] = *(const uint2*)(Arow + k0 + q * 8);
        ua.u2[1] = *(const uint2*)(Arow + k0 + q * 8 + 4);
        bf16x8 av = ua.v;
        bf16x8 b0 = *(const bf16x8*)(Bp0 + k0);
        bf16x8 b1 = *(const bf16x8*)(Bp1 + k0);
        acc0 = __builtin_amdgcn_mfma_f32_16x16x32_bf16(av, b0, acc0, 0, 0, 0);
        acc1 = __builtin_amdgcn_mfma_f32_16x16x32_bf16(av, b1, acc1, 0, 0, 0);
    }
#pragma unroll
    for (int ct = 0; ct < 2; ++ct) {
        int cc = colw0 + ct * 16 + n16;
        float s = 0.f, s2 = 0.f;
#pragma unroll
        for (int reg = 0; reg < 4; ++reg) {
            int r = row0 + q * 4 + reg;                     // C/D: row = q*4+reg
            if (r < NN) {
                float v = (ct == 0) ? acc0[reg] : acc1[reg];
                gdst[(size_t)r * DIM + cc] = f2bf(v);
                s += v; s2 += v * v;
            }
        }
        s  += __shfl_xor(s, 16);  s  += __shfl_xor(s, 32);  // reduce 4 q-groups
        s2 += __shfl_xor(s2, 16); s2 += __shfl_xor(s2, 32);
        if (lane < 16) {
            atomicAdd(&statsL[cc], s);
            atomicAdd(&statsL[DIM + cc], s2);
        }
    }
}

// ---------------- final BN + sigmoid -> out (R10 verbatim) ----------------
__global__ __launch_bounds__(256) void k_norm(Params P) {
    const float* statsL = P.stats + 2 * 2 * DIM;
    int t = threadIdx.x;
    int c8 = (t & 31) * 8;
    int r = blockIdx.x * 8 + (t >> 5);                      // grid 1250
    float sc[8], sh[8];
#pragma unroll
    for (int i = 0; i < 8; ++i) {
        int c = c8 + i;
        float mu  = statsL[c] * (1.0f / NN);
        float var = statsL[DIM + c] * (1.0f / NN) - mu * mu;
        float k = rsqrtf(var + EPS_BN) * P.g2[c];
        sc[i] = k;
        sh[i] = P.be2[c] - mu * k;
    }
    uint4 v = *(const uint4*)(P.z0 + (size_t)r * DIM + c8);
    float f[8] = {bflo(v.x), bfhi(v.x), bflo(v.y), bfhi(v.y),
                  bflo(v.z), bfhi(v.z), bflo(v.w), bfhi(v.w)};
#pragma unroll
    for (int i = 0; i < 8; ++i) f[i] = f[i] * sc[i] + sh[i];
    float4 o0, o1;
    o0.x = 1.0f / (1.0f + __expf(-f[0]));
    o0.y = 1.0f / (1.0f + __expf(-f[1]));
    o0.z = 1.0f / (1.0f + __expf(-f[2]));
    o0.w = 1.0f / (1.0f + __expf(-f[3]));
    o1.x = 1.0f / (1.0f + __expf(-f[4]));
    o1.y = 1.0f / (1.0f + __expf(-f[5]));
    o1.z = 1.0f / (1.0f + __expf(-f[6]));
    o1.w = 1.0f / (1.0f + __expf(-f[7]));
    *(float4*)(P.out + (size_t)r * DIM + c8)     = o0;
    *(float4*)(P.out + (size_t)r * DIM + c8 + 4) = o1;
}

extern "C" void kernel_launch(void* const* d_in, const int* in_sizes, int n_in,
                              void* d_out, int out_size, void* d_ws, size_t ws_size,
                              hipStream_t stream) {
    Params P;
    P.x   = (const float*)d_in[0];
    P.src = (const int*)d_in[1];
    P.dst = (const int*)d_in[2];
    P.Ws0 = (const float*)d_in[3];  P.Wn0 = (const float*)d_in[4];
    P.g0  = (const float*)d_in[6];  P.be0 = (const float*)d_in[7];
    P.Ws1 = (const float*)d_in[8];  P.Wn1 = (const float*)d_in[9];
    P.g1  = (const float*)d_in[11]; P.be1 = (const float*)d_in[12];
    P.Ws2 = (const float*)d_in[13]; P.Wn2 = (const float*)d_in[14];
    P.g2  = (const float*)d_in[16]; P.be2 = (const float*)d_in[17];
    P.out = (float*)d_out;

    char* ws = (char*)d_ws;
    size_t off = 0;
    P.hx   = (unsigned short*)(ws + off); off += (size_t)NN * DIM * 2;       // 5.12 MB
    P.z0   = (unsigned short*)(ws + off); off += (size_t)NN * DIM * 2;       // 5.12 MB
    P.z1   = (unsigned short*)(ws + off); off += (size_t)NN * DIM * 2;       // 5.12 MB
    P.wcat = (unsigned short*)(ws + off); off += (size_t)3 * DIM * KK * 2;   // 0.79 MB
    P.stats = (float*)(ws + off); off += 3 * 2 * DIM * sizeof(float);
    P.cnt   = (int*)(ws + off); off += (size_t)NN * 4; off = (off + 255) & ~(size_t)255;
    P.slots = (int*)(ws + off); off += (size_t)NN * CAP * 4;                 // 5.12 MB
    (void)ws_size;

    k_prep<<<512, 256, 0, stream>>>(P);
    k_bucket<<<(EE + 255) / 256, 256, 0, stream>>>(P);
    // ping-pong: L0 hx->z0, L1 z0->z1, L2 z1->z0 (gather src != gemm dst)
    k_ag<<<626, 512, 0, stream>>>(P, 0, P.hx, P.z0);
    k_ag<<<626, 512, 0, stream>>>(P, 1, P.z0, P.z1);
    k_ag<<<626, 512, 0, stream>>>(P, 2, P.z1, P.z0);
    k_norm<<<NN / 8, 256, 0, stream>>>(P);
}

// Round 14
// 223.655 us; speedup vs baseline: 1.1697x; 1.1442x over previous
//
#include <hip/hip_runtime.h>
#include <math.h>

#define NN 10000
#define EE 160000
#define DIM 256
#define KK 512            // concatenated K = 2*DIM
#define CAP 128           // bucket capacity (max deg ~45 for mean-16 degrees)
#define EPS_BN 1e-5f
#define AST 516           // LDS A-tile row stride in shorts (1032 B = 8B-aligned, 2-way banks)

typedef __attribute__((ext_vector_type(8)))  short bf16x8;
typedef __attribute__((ext_vector_type(16))) float f32x16;

union U16 { uint2 u2[2]; bf16x8 v; };

static __device__ __forceinline__ unsigned short f2bf(float f) {
    unsigned u = __float_as_uint(f);
    unsigned r = (u + 0x7fffu + ((u >> 16) & 1u)) >> 16;   // RTNE
    return (unsigned short)r;
}
static __device__ __forceinline__ float bflo(unsigned v) { return __uint_as_float(v << 16); }
static __device__ __forceinline__ float bfhi(unsigned v) { return __uint_as_float(v & 0xffff0000u); }
static __device__ __forceinline__ unsigned packbf(float a, float b) {
    return (unsigned)f2bf(a) | ((unsigned)f2bf(b) << 16);
}

struct Params {
    const float* x; const int* src; const int* dst;
    const float *Ws0, *Wn0, *Ws1, *Wn1, *Ws2, *Wn2;
    const float *g0, *be0, *g1, *be1, *g2, *be2;
    float* out;
    unsigned short* hx;     // [NN][DIM] bf16 x   (row = 32 uint4)
    unsigned short* z0;     // [NN][DIM] bf16 z ping
    unsigned short* z1;     // [NN][DIM] bf16 z pong
    unsigned short* wcat;   // [3][DIM][KK] bf16, [n][k]
    float* stats;           // [3][2*DIM]
    int* cnt;               // [NN]
    int* slots;             // [NN][CAP]
};

static __device__ __forceinline__ void accum8(float* a, uint4 v) {
    a[0] += bflo(v.x); a[1] += bfhi(v.x);
    a[2] += bflo(v.y); a[3] += bfhi(v.y);
    a[4] += bflo(v.z); a[5] += bfhi(v.z);
    a[6] += bflo(v.w); a[7] += bfhi(v.w);
}
static __device__ __forceinline__ void accum8n(float* a, uint4 v,
                                               const float* sc, const float* sh) {
    a[0] += fmaxf(bflo(v.x) * sc[0] + sh[0], 0.f);
    a[1] += fmaxf(bfhi(v.x) * sc[1] + sh[1], 0.f);
    a[2] += fmaxf(bflo(v.y) * sc[2] + sh[2], 0.f);
    a[3] += fmaxf(bfhi(v.y) * sc[3] + sh[3], 0.f);
    a[4] += fmaxf(bflo(v.z) * sc[4] + sh[4], 0.f);
    a[5] += fmaxf(bfhi(v.z) * sc[5] + sh[5], 0.f);
    a[6] += fmaxf(bflo(v.w) * sc[6] + sh[6], 0.f);
    a[7] += fmaxf(bfhi(v.w) * sc[7] + sh[7], 0.f);
}

// ---------------- prep: converts + zeroing ----------------
__global__ __launch_bounds__(256) void k_prep(Params P) {
    int g0 = blockIdx.x * 256 + threadIdx.x;
    int stride = gridDim.x * 256;
    for (int g = g0; g < NN * 64; g += stride) {            // x -> hx bf16 [NN][256]
        int r = g >> 6, c4 = (g & 63) * 4;
        float4 v = *(const float4*)(P.x + (size_t)r * DIM + c4);
        uint2 p; p.x = packbf(v.x, v.y); p.y = packbf(v.z, v.w);
        *(uint2*)(P.hx + (size_t)r * DIM + c4) = p;
    }
    for (int g = g0; g < 3 * DIM * KK; g += stride) {       // [Ws;Wn] -> wcat [n][k]
        int L = g >> 17; int i = g & 131071;
        int k = i >> 8, n = i & 255;
        const float* Ws = (L == 0) ? P.Ws0 : ((L == 1) ? P.Ws1 : P.Ws2);
        const float* Wn = (L == 0) ? P.Wn0 : ((L == 1) ? P.Wn1 : P.Wn2);
        float v = (k < DIM) ? Ws[(size_t)k * DIM + n] : Wn[(size_t)(k - DIM) * DIM + n];
        P.wcat[(size_t)L * DIM * KK + (size_t)n * KK + k] = f2bf(v);
    }
    for (int g = g0; g < NN + 6 * DIM; g += stride) {
        if (g < NN) P.cnt[g] = 0;
        else P.stats[g - NN] = 0.f;
    }
}

// ---------------- bucket build ----------------
__global__ __launch_bounds__(256) void k_bucket(Params P) {
    int e = blockIdx.x * 256 + threadIdx.x;
    if (e < EE) {
        int d = P.dst[e];
        int p = atomicAdd(&P.cnt[d], 1);
        if (p < CAP) P.slots[(size_t)d * CAP + p] = P.src[e];
    }
}

// ---------------- fused agg + GEMM + stats, one layer (R10 config) ----------
// grid = 313 x 512 threads (8 waves). Phase A: wave gathers 4 nodes (wave-per-
// node, half-waves interleave edges, 4-deep unroll) into LDS A-tile [32][512]
// (+ own rows, BN+relu-normalized for L>0). Phase B: wave w = cols
// w*32..w*32+31 via one 32x32x16 MFMA chain; A from LDS, B from wcat.
// Ping-pong: gsrc != gdst always.
__global__ __launch_bounds__(512) void k_ag(Params P, int L,
                                            const unsigned short* __restrict__ gsrc,
                                            unsigned short* __restrict__ gdst) {
    __shared__ unsigned short At[32][AST];                  // 33 KB
    int t = threadIdx.x;
    int wave = t >> 6, lane = t & 63;
    int h = lane >> 5, l = lane & 31;

    float sc[8], sh[8];
    if (L > 0) {                                            // BN affine of prev layer
        const float* st = P.stats + (L - 1) * 2 * DIM;
        const float* gam = (L == 1) ? P.g0 : P.g1;
        const float* bet = (L == 1) ? P.be0 : P.be1;
#pragma unroll
        for (int i = 0; i < 8; ++i) {
            int c = l * 8 + i;
            float mu  = st[c] * (1.0f / NN);
            float var = st[DIM + c] * (1.0f / NN) - mu * mu;
            float k = rsqrtf(var + EPS_BN) * gam[c];
            sc[i] = k;
            sh[i] = bet[c] - mu * k;
        }
    }
    const uint4* srcm = (const uint4*)gsrc;                 // rows = 32 uint4

    // ================= phase A: wave per node, 4 nodes =================
    for (int i = 0; i < 4; ++i) {
        int m = wave * 4 + i;                               // 8 waves x 4 = 32 rows
        int node = blockIdx.x * 32 + m;
        unsigned short* arow = &At[m][0];
        if (node >= NN) {
            if (h == 0) {
                uint2 z2 = make_uint2(0u, 0u);
                *(uint2*)(arow + l * 8)           = z2;
                *(uint2*)(arow + l * 8 + 4)       = z2;
                *(uint2*)(arow + 256 + l * 8)     = z2;
                *(uint2*)(arow + 256 + l * 8 + 4) = z2;
            }
            continue;
        }
        int cnt = P.cnt[node]; if (cnt > CAP) cnt = CAP;
        const int* sl = P.slots + (size_t)node * CAP;
        if (h == 0) {                                       // own row -> A left half
            uint4 z = srcm[(size_t)node * 32 + l];
            uint4 o;
            if (L > 0) {
                o.x = packbf(fmaxf(bflo(z.x) * sc[0] + sh[0], 0.f),
                             fmaxf(bfhi(z.x) * sc[1] + sh[1], 0.f));
                o.y = packbf(fmaxf(bflo(z.y) * sc[2] + sh[2], 0.f),
                             fmaxf(bfhi(z.y) * sc[3] + sh[3], 0.f));
                o.z = packbf(fmaxf(bflo(z.z) * sc[4] + sh[4], 0.f),
                             fmaxf(bfhi(z.z) * sc[5] + sh[5], 0.f));
                o.w = packbf(fmaxf(bflo(z.w) * sc[6] + sh[6], 0.f),
                             fmaxf(bfhi(z.w) * sc[7] + sh[7], 0.f));
            } else o = z;
            *(uint2*)(arow + l * 8)     = make_uint2(o.x, o.y);
            *(uint2*)(arow + l * 8 + 4) = make_uint2(o.z, o.w);
        }
        float a[8] = {0, 0, 0, 0, 0, 0, 0, 0};
        int j = h;                                          // half-waves interleave edges
        if (L == 0) {
            for (; j + 6 < cnt; j += 8) {
                uint4 v0 = srcm[(size_t)sl[j + 0] * 32 + l];
                uint4 v1 = srcm[(size_t)sl[j + 2] * 32 + l];
                uint4 v2 = srcm[(size_t)sl[j + 4] * 32 + l];
                uint4 v3 = srcm[(size_t)sl[j + 6] * 32 + l];
                accum8(a, v0); accum8(a, v1); accum8(a, v2); accum8(a, v3);
            }
            for (; j < cnt; j += 2) accum8(a, srcm[(size_t)sl[j] * 32 + l]);
        } else {
            for (; j + 6 < cnt; j += 8) {
                uint4 v0 = srcm[(size_t)sl[j + 0] * 32 + l];
                uint4 v1 = srcm[(size_t)sl[j + 2] * 32 + l];
                uint4 v2 = srcm[(size_t)sl[j + 4] * 32 + l];
                uint4 v3 = srcm[(size_t)sl[j + 6] * 32 + l];
                accum8n(a, v0, sc, sh); accum8n(a, v1, sc, sh);
                accum8n(a, v2, sc, sh); accum8n(a, v3, sc, sh);
            }
            for (; j < cnt; j += 2) accum8n(a, srcm[(size_t)sl[j] * 32 + l], sc, sh);
        }
#pragma unroll
        for (int q = 0; q < 8; ++q) a[q] += __shfl_xor(a[q], 32);
        if (h == 0) {                                       // mean -> A right half
            float inv = 1.0f / (float)(cnt > 1 ? cnt : 1);
            *(uint2*)(arow + 256 + l * 8)     = make_uint2(packbf(a[0] * inv, a[1] * inv),
                                                           packbf(a[2] * inv, a[3] * inv));
            *(uint2*)(arow + 256 + l * 8 + 4) = make_uint2(packbf(a[4] * inv, a[5] * inv),
                                                           packbf(a[6] * inv, a[7] * inv));
        }
    }
    __syncthreads();

    // ================= phase B: one 32x32x16 MFMA chain per wave =================
    const unsigned short* wcatL = P.wcat + (size_t)L * DIM * KK;
    float* statsL = P.stats + L * 2 * DIM;
    int m = l;
    int row0 = blockIdx.x * 32;
    int colw0 = wave * 32;                                  // 8 waves x 32 = 256 cols
    const unsigned short* Bp = wcatL + (size_t)(colw0 + m) * KK + h * 8;
    const unsigned short* Arow = &At[m][0];
    f32x16 acc;
#pragma unroll
    for (int i = 0; i < 16; ++i) acc[i] = 0.f;
#pragma unroll 8
    for (int k0 = 0; k0 < KK; k0 += 16) {
        U16 ua;
        ua.u2[0] = *(const uint2*)(Arow + k0 + h * 8);
        ua.u2[1] = *(const uint2*)(Arow + k0 + h * 8 + 4);
        bf16x8 av = ua.v;
        bf16x8 bv = *(const bf16x8*)(Bp + k0);
        acc = __builtin_amdgcn_mfma_f32_32x32x16_bf16(av, bv, acc, 0, 0, 0);
    }
    int cc = colw0 + m;
    float s = 0.f, s2 = 0.f;
#pragma unroll
    for (int reg = 0; reg < 16; ++reg) {
        int r = row0 + (reg & 3) + 8 * (reg >> 2) + 4 * h;
        if (r < NN) {
            float v = acc[reg];
            gdst[(size_t)r * DIM + cc] = f2bf(v);
            s += v; s2 += v * v;
        }
    }
    s  += __shfl_down(s, 32);
    s2 += __shfl_down(s2, 32);
    if (h == 0) {
        atomicAdd(&statsL[cc], s);
        atomicAdd(&statsL[DIM + cc], s2);
    }
}

// ---------------- final BN + sigmoid -> out (fp32) ----------------
__global__ __launch_bounds__(256) void k_norm(Params P) {
    const float* statsL = P.stats + 2 * 2 * DIM;
    int t = threadIdx.x;
    int c8 = (t & 31) * 8;
    int r = blockIdx.x * 8 + (t >> 5);                      // grid 1250
    float sc[8], sh[8];
#pragma unroll
    for (int i = 0; i < 8; ++i) {
        int c = c8 + i;
        float mu  = statsL[c] * (1.0f / NN);
        float var = statsL[DIM + c] * (1.0f / NN) - mu * mu;
        float k = rsqrtf(var + EPS_BN) * P.g2[c];
        sc[i] = k;
        sh[i] = P.be2[c] - mu * k;
    }
    uint4 v = *(const uint4*)(P.z0 + (size_t)r * DIM + c8);
    float f[8] = {bflo(v.x), bfhi(v.x), bflo(v.y), bfhi(v.y),
                  bflo(v.z), bfhi(v.z), bflo(v.w), bfhi(v.w)};
#pragma unroll
    for (int i = 0; i < 8; ++i) f[i] = f[i] * sc[i] + sh[i];
    float4 o0, o1;
    o0.x = 1.0f / (1.0f + __expf(-f[0]));
    o0.y = 1.0f / (1.0f + __expf(-f[1]));
    o0.z = 1.0f / (1.0f + __expf(-f[2]));
    o0.w = 1.0f / (1.0f + __expf(-f[3]));
    o1.x = 1.0f / (1.0f + __expf(-f[4]));
    o1.y = 1.0f / (1.0f + __expf(-f[5]));
    o1.z = 1.0f / (1.0f + __expf(-f[6]));
    o1.w = 1.0f / (1.0f + __expf(-f[7]));
    *(float4*)(P.out + (size_t)r * DIM + c8)     = o0;
    *(float4*)(P.out + (size_t)r * DIM + c8 + 4) = o1;
}

extern "C" void kernel_launch(void* const* d_in, const int* in_sizes, int n_in,
                              void* d_out, int out_size, void* d_ws, size_t ws_size,
                              hipStream_t stream) {
    Params P;
    P.x   = (const float*)d_in[0];
    P.src = (const int*)d_in[1];
    P.dst = (const int*)d_in[2];
    P.Ws0 = (const float*)d_in[3];  P.Wn0 = (const float*)d_in[4];
    P.g0  = (const float*)d_in[6];  P.be0 = (const float*)d_in[7];
    P.Ws1 = (const float*)d_in[8];  P.Wn1 = (const float*)d_in[9];
    P.g1  = (const float*)d_in[11]; P.be1 = (const float*)d_in[12];
    P.Ws2 = (const float*)d_in[13]; P.Wn2 = (const float*)d_in[14];
    P.g2  = (const float*)d_in[16]; P.be2 = (const float*)d_in[17];
    P.out = (float*)d_out;

    char* ws = (char*)d_ws;
    size_t off = 0;
    P.hx   = (unsigned short*)(ws + off); off += (size_t)NN * DIM * 2;       // 5.12 MB
    P.z0   = (unsigned short*)(ws + off); off += (size_t)NN * DIM * 2;       // 5.12 MB
    P.z1   = (unsigned short*)(ws + off); off += (size_t)NN * DIM * 2;       // 5.12 MB
    P.wcat = (unsigned short*)(ws + off); off += (size_t)3 * DIM * KK * 2;   // 0.79 MB
    P.stats = (float*)(ws + off); off += 3 * 2 * DIM * sizeof(float);
    P.cnt   = (int*)(ws + off); off += (size_t)NN * 4; off = (off + 255) & ~(size_t)255;
    P.slots = (int*)(ws + off); off += (size_t)NN * CAP * 4;                 // 5.12 MB
    (void)ws_size;

    k_prep<<<512, 256, 0, stream>>>(P);
    k_bucket<<<(EE + 255) / 256, 256, 0, stream>>>(P);
    // ping-pong: L0 hx->z0, L1 z0->z1, L2 z1->z0 (gather src != gemm dst)
    k_ag<<<313, 512, 0, stream>>>(P, 0, P.hx, P.z0);
    k_ag<<<313, 512, 0, stream>>>(P, 1, P.z0, P.z1);
    k_ag<<<313, 512, 0, stream>>>(P, 2, P.z1, P.z0);
    k_norm<<<NN / 8, 256, 0, stream>>>(P);
}